// Round 1
// baseline (7341.621 us; speedup 1.0000x reference)
//
#include <hip/hip_runtime.h>

// Seq2Seq round 5:
//  - Persistent single-launch encoder (h/c kept in LDS/registers, no grid sync
//    needed: each block owns 16 batch rows x all 1024 gate cols of one chain).
//  - A_c / A_p precompute (t-invariant attention projections, as in reference)
//    => per-decoder-step attention collapses to ONE block-local kernel
//    (attn_both), cutting decoder from 6 to 3 launches/step.
//  - Runtime workspace guard: if ws too small for A_c/A_p, fall back to the
//    previous per-step u_c/u_p GEMM path.

typedef unsigned short u16;
typedef __attribute__((ext_vector_type(8))) short bf16x8;
typedef __attribute__((ext_vector_type(4))) float f32x4;

#define DEVFN static __device__ __forceinline__

DEVFN float bf2f(u16 u) {
  unsigned int x = ((unsigned int)u) << 16;
  float f; __builtin_memcpy(&f, &x, 4); return f;
}
DEVFN u16 f2bf(float f) {
  unsigned int x; __builtin_memcpy(&x, &f, 4);
  x = (x + 0x7fffu + ((x >> 16) & 1u)) >> 16;
  return (u16)x;
}
DEVFN float sigf(float x) { return 1.f / (1.f + __expf(-x)); }
DEVFN bf16x8 load8(const u16* p) { return *(const bf16x8*)p; }
DEVFN int clampi(int v, int lo, int hi) { return v < lo ? lo : (v > hi ? hi : v); }

// ---------------------------------------------------------------------------
// Generic MFMA GEMM: out[m,n] = sum_k A[m,k] * W[n,k]  (A,W bf16)
// EPI 0: f32 out (+bias). EPI 1: bf16 out (no bias). EPI 2: hk epilogue.
// ---------------------------------------------------------------------------
struct GemmArgs {
  const u16* A; int lda; int M;
  const u16* W; int ldw; int N; int K;
  void* out; int ldc;
  const float* bias;
  const float* hk_base; const float* proj_act; const int* actions; int t;
};

template <int EPI>
__global__ __launch_bounds__(256) void gemm_k(GemmArgs g) {
  int lane = threadIdx.x & 63;
  int wave = threadIdx.x >> 6;
  int col = lane & 15, q = lane >> 4;
  int m0 = blockIdx.x * 64 + (wave >> 1) * 32;
  int n0 = blockIdx.y * 64 + (wave & 1) * 32;
  f32x4 acc[2][2] = {};
  int rA[2] = { m0 + col, m0 + 16 + col };
  int rB[2] = { n0 + col, n0 + 16 + col };
  bool gA[2] = { rA[0] < g.M, rA[1] < g.M };
  bool gB[2] = { rB[0] < g.N, rB[1] < g.N };
  const u16* pA[2]; const u16* pB[2];
#pragma unroll
  for (int i = 0; i < 2; i++) {
    pA[i] = g.A + (size_t)(gA[i] ? rA[i] : 0) * g.lda + q * 8;
    pB[i] = g.W + (size_t)(gB[i] ? rB[i] : 0) * g.ldw + q * 8;
  }
  bf16x8 zf = {0,0,0,0,0,0,0,0};
  for (int k = 0; k < g.K; k += 32) {
    bf16x8 a0 = gA[0] ? load8(pA[0] + k) : zf;
    bf16x8 a1 = gA[1] ? load8(pA[1] + k) : zf;
    bf16x8 b0 = gB[0] ? load8(pB[0] + k) : zf;
    bf16x8 b1 = gB[1] ? load8(pB[1] + k) : zf;
    acc[0][0] = __builtin_amdgcn_mfma_f32_16x16x32_bf16(a0, b0, acc[0][0], 0, 0, 0);
    acc[0][1] = __builtin_amdgcn_mfma_f32_16x16x32_bf16(a0, b1, acc[0][1], 0, 0, 0);
    acc[1][0] = __builtin_amdgcn_mfma_f32_16x16x32_bf16(a1, b0, acc[1][0], 0, 0, 0);
    acc[1][1] = __builtin_amdgcn_mfma_f32_16x16x32_bf16(a1, b1, acc[1][1], 0, 0, 0);
  }
#pragma unroll
  for (int mi = 0; mi < 2; mi++)
#pragma unroll
    for (int ni = 0; ni < 2; ni++)
#pragma unroll
      for (int r = 0; r < 4; r++) {
        int m = m0 + mi * 16 + q * 4 + r;
        int n = n0 + ni * 16 + col;
        if (m >= g.M || n >= g.N) continue;
        float v = acc[mi][ni][r];
        if constexpr (EPI == 0) {
          if (g.bias) v += g.bias[n];
          ((float*)g.out)[(size_t)m * g.ldc + n] = v;
        } else if constexpr (EPI == 1) {
          ((u16*)g.out)[(size_t)m * g.ldc + n] = f2bf(v);
        } else { // EPI 2: hk = tanh(acc + hk_base + proj_act[action]) -> bf16
          int act = clampi(g.actions[m * 32 + g.t], 0, 99);
          v += g.hk_base[m * 512 + n] + g.proj_act[(size_t)act * 512 + n];
          ((u16*)g.out)[(size_t)m * g.ldc + n] = f2bf(tanhf(v));
        }
      }
}

// ---------------------------------------------------------------------------
// Decoder gates GEMM + fused LSTM cell. Interleaved gate rows r=(j*4+g).
// ---------------------------------------------------------------------------
__global__ __launch_bounds__(256) void dec_gates_cell(
    const u16* zin_cur, const u16* Wih, const u16* Whh, const float* bias_int,
    float* c_ws, u16* zin_nxt, u16* qbuf, u16* outs, int t) {
  int lane = threadIdx.x & 63, wave = threadIdx.x >> 6;
  int col = lane & 15, q = lane >> 4;
  int m0 = blockIdx.x * 64 + (wave >> 1) * 32;
  int n0 = blockIdx.y * 64 + (wave & 1) * 32;
  f32x4 acc[2][2] = {};
  const u16* pA[2]; const u16* pI[2]; const u16* pH[2];
#pragma unroll
  for (int i = 0; i < 2; i++) {
    pA[i] = zin_cur + (size_t)(m0 + i * 16 + col) * 1024 + q * 8;
    int r = n0 + i * 16 + col;
    int src = (r & 3) * 512 + (r >> 2);
    pI[i] = Wih + (size_t)src * 512 + q * 8;
    pH[i] = Whh + (size_t)src * 512 + q * 8;
  }
  for (int k = 0; k < 512; k += 32) {
    bf16x8 a0 = load8(pA[0] + k);
    bf16x8 a1 = load8(pA[1] + k);
    bf16x8 b0 = load8(pI[0] + k);
    bf16x8 b1 = load8(pI[1] + k);
    acc[0][0] = __builtin_amdgcn_mfma_f32_16x16x32_bf16(a0, b0, acc[0][0], 0, 0, 0);
    acc[0][1] = __builtin_amdgcn_mfma_f32_16x16x32_bf16(a0, b1, acc[0][1], 0, 0, 0);
    acc[1][0] = __builtin_amdgcn_mfma_f32_16x16x32_bf16(a1, b0, acc[1][0], 0, 0, 0);
    acc[1][1] = __builtin_amdgcn_mfma_f32_16x16x32_bf16(a1, b1, acc[1][1], 0, 0, 0);
  }
  for (int k = 0; k < 512; k += 32) {
    bf16x8 a0 = load8(pA[0] + 512 + k);
    bf16x8 a1 = load8(pA[1] + 512 + k);
    bf16x8 b0 = load8(pH[0] + k);
    bf16x8 b1 = load8(pH[1] + k);
    acc[0][0] = __builtin_amdgcn_mfma_f32_16x16x32_bf16(a0, b0, acc[0][0], 0, 0, 0);
    acc[0][1] = __builtin_amdgcn_mfma_f32_16x16x32_bf16(a0, b1, acc[0][1], 0, 0, 0);
    acc[1][0] = __builtin_amdgcn_mfma_f32_16x16x32_bf16(a1, b0, acc[1][0], 0, 0, 0);
    acc[1][1] = __builtin_amdgcn_mfma_f32_16x16x32_bf16(a1, b1, acc[1][1], 0, 0, 0);
  }
  __shared__ float ls[64][68];
#pragma unroll
  for (int mi = 0; mi < 2; mi++)
#pragma unroll
    for (int ni = 0; ni < 2; ni++)
#pragma unroll
      for (int r = 0; r < 4; r++) {
        int nl = (wave & 1) * 32 + ni * 16 + col;
        int ml = (wave >> 1) * 32 + mi * 16 + q * 4 + r;
        ls[ml][nl] = acc[mi][ni][r] + bias_int[blockIdx.y * 64 + nl];
      }
  __syncthreads();
  int m = threadIdx.x & 63, grp = threadIdx.x >> 6;
  int gm = blockIdx.x * 64 + m;
  int j0 = blockIdx.y * 16;
#pragma unroll
  for (int jl = 0; jl < 4; jl++) {
    int jc = grp * 4 + jl;
    float gi = ls[m][jc * 4 + 0];
    float gf = ls[m][jc * 4 + 1];
    float gg = ls[m][jc * 4 + 2];
    float go = ls[m][jc * 4 + 3];
    int j = j0 + jc;
    float cn = sigf(gf) * c_ws[gm * 512 + j] + sigf(gi) * tanhf(gg);
    c_ws[gm * 512 + j] = cn;
    float hn = sigf(go) * tanhf(cn);
    u16 hb = f2bf(hn);
    zin_nxt[(size_t)gm * 1024 + 512 + j] = hb;
    qbuf[(size_t)gm * 1024 + j] = hb;
    outs[((size_t)gm * 32 + t) * 512 + j] = hb;
  }
}

// ---------------------------------------------------------------------------
// prep kernels (f32 inputs)
// ---------------------------------------------------------------------------
__global__ void cvt_slice(const float* in, int ld, int c0, u16* out, int R, int C) {
  int idx = blockIdx.x * 256 + threadIdx.x;
  if (idx >= R * C) return;
  int r = idx / C, c = idx - r * C;
  out[idx] = f2bf(in[(size_t)r * ld + c0 + c]);
}

// transposed convert: out[c*R + r] = bf16(in[r*C + c])
__global__ void cvtT(const float* in, u16* out, int R, int C) {
  int idx = blockIdx.x * 256 + threadIdx.x;
  if (idx >= R * C) return;
  int r = idx / C, c = idx - r * C;
  out[(size_t)c * R + r] = f2bf(in[idx]);
}

__global__ void addcvt(const float* a, const float* b, float* o, int n) {
  int i = blockIdx.x * 256 + threadIdx.x;
  if (i < n) o[i] = a[i] + (b ? b[i] : 0.f);
}

__global__ void bdecint_build(const float* bih, const float* bhh, float* o) {
  int r = blockIdx.x * 256 + threadIdx.x; // 2048
  int j = r >> 2, gg = r & 3;
  o[r] = bih[gg * 512 + j] + bhh[gg * 512 + j];
}

__global__ void wsum_build(const float* Wbd, u16* Wsum) {
  int idx = blockIdx.x * 256 + threadIdx.x; // 512*896
  int n = idx / 896, j = idx % 896;
  int c1 = (j < 448) ? (1024 + j) : (1920 + (j - 448));
  int c2 = c1 + 448;
  Wsum[idx] = f2bf(Wbd[(size_t)n * 2944 + c1] + Wbd[(size_t)n * 2944 + c2]);
}

// ---------------------------------------------------------------------------
// Env encoder (unchanged): 1792 independent 4-step LSTM chains -> ctx_cat
// ---------------------------------------------------------------------------
__global__ __launch_bounds__(256) void env_encode(
    const int* cur_env, const int* ini_env,
    const float* color_emb, const float* pos_emb,
    const float* wih, const float* whh, const float* bih, const float* bhh,
    u16* ctx_cat) {
  __shared__ float s_wih[128 * 33], s_whh[128 * 33], s_b[128], s_col[7 * 32];
  __shared__ float h_lds[8][33];
  int tid = threadIdx.x;
  for (int i = tid; i < 128 * 32; i += 256) {
    int r = i >> 5, k2 = i & 31;
    s_wih[r * 33 + k2] = wih[i];
    s_whh[r * 33 + k2] = whh[i];
  }
  for (int i = tid; i < 128; i += 256) s_b[i] = bih[i] + bhh[i];
  for (int i = tid; i < 224; i += 256) s_col[i] = color_emb[i];
  int sl = tid >> 5, j = tid & 31;
  int gseq = blockIdx.x * 8 + sl;
  int e = gseq / 896, rem = gseq % 896;
  int b = rem / 7, p = rem % 7;
  const int* env = e ? ini_env : cur_env;
  int eoff = e ? 0 : 448;
  h_lds[sl][j] = 0.f;
  __syncthreads();
  float cj = 0.f, hj = 0.f;
  for (int st = 0; st < 4; st++) {
    int tok = clampi(env[b * 35 + p * 5 + 1 + st], 0, 6);
    const float* x = &s_col[tok * 32];
    float pi = s_b[j], pf = s_b[32 + j], pg = s_b[64 + j], po = s_b[96 + j];
    for (int k = 0; k < 32; k++) {
      float xk = x[k], hk = h_lds[sl][k];
      pi += s_wih[j * 33 + k] * xk + s_whh[j * 33 + k] * hk;
      pf += s_wih[(32 + j) * 33 + k] * xk + s_whh[(32 + j) * 33 + k] * hk;
      pg += s_wih[(64 + j) * 33 + k] * xk + s_whh[(64 + j) * 33 + k] * hk;
      po += s_wih[(96 + j) * 33 + k] * xk + s_whh[(96 + j) * 33 + k] * hk;
    }
    cj = sigf(pf) * cj + sigf(pi) * tanhf(pg);
    hj = sigf(po) * tanhf(cj);
    __syncthreads();
    h_lds[sl][j] = hj;
    __syncthreads();
  }
  size_t base = (size_t)b * 896 + eoff + p * 64;
  ctx_cat[base + j] = f2bf(pos_emb[p * 32 + j]);
  ctx_cat[base + 32 + j] = f2bf(hj);
}

// ---------------------------------------------------------------------------
// PERSISTENT encoder: ONE launch, 32 blocks = 4 chains x 8 row-groups.
// Block owns 16 batch rows, computes all 1024 gate cols each step.
// h lives in LDS (bf16, padded), c lives in registers. No grid sync needed:
// the LSTM recurrence is independent per batch row.
// Wave w handles gate-col slice j in [w*64, w*64+64) for ALL 4 gates, so each
// lane ends up holding i,f,g,o for its own (batch,j) cells -> in-lane cell
// update, no LDS gate exchange.
// ---------------------------------------------------------------------------
__global__ __launch_bounds__(256) void enc_persist(
    const int* ins_tok, const int* his_tok, const u16* enc_emb,
    const u16* wih_f, const u16* wih_b, const u16* whh_f, const u16* whh_b,
    const float* bias_f, const float* bias_b,
    u16* ins_enc, u16* his_enc) {
  int chain = blockIdx.x >> 3;   // 0 ins_f, 1 ins_b, 2 his_f, 3 his_b
  int rowg = blockIdx.x & 7;     // batch rows rowg*16 .. +16
  int dir = chain & 1, his = chain >> 1;
  int L = his ? 128 : 64;
  const int* toks = his ? his_tok : ins_tok;
  const u16* wih = dir ? wih_b : wih_f;
  const u16* whh = dir ? whh_b : whh_f;
  const float* bias = dir ? bias_b : bias_f;
  u16* out = his ? his_enc : ins_enc;

  __shared__ u16 h_lds[16][264];  // row stride 264 (528B = 33*16B): aligned, low-conflict

  int tid = threadIdx.x;
  int w = tid >> 6, lane = tid & 63;
  int col = lane & 15, q = lane >> 4;
  int rowbase = rowg * 16;

  // t-invariant bases. weight row for (gate G, local nn): (G*256 + w*64 + nn*16 + col)
  const u16* wib = wih + (size_t)(w * 64 + col) * 128 + q * 8;
  const u16* whb = whh + (size_t)(w * 64 + col) * 256 + q * 8;
  const int* tokp = toks + (size_t)(rowbase + col) * L;

  // per-lane biases for the 16 (G,nn) gate slots this lane owns
  float bias_r[4][4];
#pragma unroll
  for (int G = 0; G < 4; G++)
#pragma unroll
    for (int nn = 0; nn < 4; nn++)
      bias_r[G][nn] = bias[G * 256 + w * 64 + nn * 16 + col];

  float creg[4][4] = {};  // c state: [nn(j)][r(batch)]

  for (int t = 0; t < L; t++) {
    int t_x = dir ? (L - 1 - t) : t;
    f32x4 acc[4][4] = {};  // [G][nn]
    // x-part: emb[tok] @ Wih^T (gathered A rows, per-lane token)
    int tok = clampi(tokp[t_x], 0, 1999);
    const u16* xrow = enc_emb + (size_t)tok * 128 + q * 8;
    for (int k = 0; k < 128; k += 32) {
      bf16x8 a = load8(xrow + k);
#pragma unroll
      for (int G = 0; G < 4; G++)
#pragma unroll
        for (int nn = 0; nn < 4; nn++) {
          bf16x8 bb = load8(wib + (size_t)(G * 256 + nn * 16) * 128 + k);
          acc[G][nn] = __builtin_amdgcn_mfma_f32_16x16x32_bf16(a, bb, acc[G][nn], 0, 0, 0);
        }
    }
    // h-part: h_prev @ Whh^T (A from LDS)
    if (t > 0) {
      for (int k = 0; k < 256; k += 32) {
        bf16x8 a = *(const bf16x8*)(&h_lds[col][k + q * 8]);
#pragma unroll
        for (int G = 0; G < 4; G++)
#pragma unroll
          for (int nn = 0; nn < 4; nn++) {
            bf16x8 bb = load8(whb + (size_t)(G * 256 + nn * 16) * 256 + k);
            acc[G][nn] = __builtin_amdgcn_mfma_f32_16x16x32_bf16(a, bb, acc[G][nn], 0, 0, 0);
          }
      }
    }
    __syncthreads();  // all h_lds(t-1) reads done before overwrite
    // in-lane cell update: lane owns batch rows q*4+r, j = w*64 + nn*16 + col
#pragma unroll
    for (int nn = 0; nn < 4; nn++)
#pragma unroll
      for (int r = 0; r < 4; r++) {
        float gi = acc[0][nn][r] + bias_r[0][nn];
        float gf = acc[1][nn][r] + bias_r[1][nn];
        float gg = acc[2][nn][r] + bias_r[2][nn];
        float go = acc[3][nn][r] + bias_r[3][nn];
        float cn = sigf(gf) * creg[nn][r] + sigf(gi) * tanhf(gg);
        creg[nn][r] = cn;
        float hn = sigf(go) * tanhf(cn);
        u16 hb = f2bf(hn);
        int bq = q * 4 + r, j = w * 64 + nn * 16 + col;
        h_lds[bq][j] = hb;
        out[((size_t)(rowbase + bq) * L + t_x) * 512 + dir * 256 + j] = hb;
      }
    __syncthreads();  // h_lds(t) complete before next step's reads
  }
}

// ---------------------------------------------------------------------------
// Fused decoder attention (A_c/A_p precomputed): per block b,
// scores_c = A_c[b]·h -> softmax -> z_c; q=[h|z_c];
// scores_p = A_p[b]·q -> softmax -> z_p; qattn[b] = [z_c | z_p].
// Replaces 4 launches (u_c GEMM, attn1, u_p GEMM, attn2).
// ---------------------------------------------------------------------------
__global__ __launch_bounds__(256) void attn_both(
    const u16* qbuf, const u16* A_c, const u16* insenc,
    const u16* A_p, const u16* hisenc, u16* qattn) {
  int b = blockIdx.x, tid = threadIdx.x;
  __shared__ float su[1024], red[256], aw[128], mr[2];
  for (int d = tid; d < 512; d += 256) su[d] = bf2f(qbuf[(size_t)b * 1024 + d]);
  __syncthreads();
  // --- attention 1 over 64 ins positions ---
  {
    int l = tid >> 2, part = tid & 3;
    const u16* row = A_c + ((size_t)b * 64 + l) * 512 + part * 128;
    float s = 0.f;
    for (int k = 0; k < 128; k += 8) {
      bf16x8 v = load8(row + k);
#pragma unroll
      for (int e = 0; e < 8; e++) s += bf2f((u16)v[e]) * su[part * 128 + k + e];
    }
    red[tid] = s;
  }
  __syncthreads();
  if (tid < 64) {
    float sc = red[tid * 4] + red[tid * 4 + 1] + red[tid * 4 + 2] + red[tid * 4 + 3];
    float m = sc;
    for (int off = 32; off > 0; off >>= 1) m = fmaxf(m, __shfl_xor(m, off));
    float e = __expf(sc - m);
    float sm = e;
    for (int off = 32; off > 0; off >>= 1) sm += __shfl_xor(sm, off);
    aw[tid] = e / sm;
  }
  __syncthreads();
  for (int d = tid; d < 512; d += 256) {
    float z = 0.f;
    for (int l = 0; l < 64; l++) z += aw[l] * bf2f(insenc[((size_t)b * 64 + l) * 512 + d]);
    su[512 + d] = z;
    qattn[(size_t)b * 1024 + d] = f2bf(z);
  }
  __syncthreads();
  // --- attention 2 over 128 his positions, q = su[0..1023] ---
  {
    int l = tid >> 1, part = tid & 1;
    const u16* row = A_p + ((size_t)b * 128 + l) * 1024 + part * 512;
    float s = 0.f;
    for (int k = 0; k < 512; k += 8) {
      bf16x8 v = load8(row + k);
#pragma unroll
      for (int e = 0; e < 8; e++) s += bf2f((u16)v[e]) * su[part * 512 + k + e];
    }
    red[tid] = s;
  }
  __syncthreads();
  float sc2 = (tid < 128) ? (red[tid * 2] + red[tid * 2 + 1]) : 0.f;
  __syncthreads();
  if (tid < 128) red[tid] = sc2;
  __syncthreads();
  if (tid < 64) {
    float m = fmaxf(red[tid], red[tid + 64]);
    for (int off = 32; off > 0; off >>= 1) m = fmaxf(m, __shfl_xor(m, off));
    if (tid == 0) mr[0] = m;
  }
  __syncthreads();
  float ex = 0.f;
  if (tid < 128) { ex = __expf(sc2 - mr[0]); red[tid] = ex; }
  __syncthreads();
  if (tid < 64) {
    float s2 = red[tid] + red[tid + 64];
    for (int off = 32; off > 0; off >>= 1) s2 += __shfl_xor(s2, off);
    if (tid == 0) mr[1] = s2;
  }
  __syncthreads();
  if (tid < 128) aw[tid] = ex / mr[1];
  __syncthreads();
  for (int d = tid; d < 512; d += 256) {
    float z = 0.f;
    for (int l = 0; l < 128; l++) z += aw[l] * bf2f(hisenc[((size_t)b * 128 + l) * 512 + d]);
    qattn[(size_t)b * 1024 + 512 + d] = f2bf(z);
  }
}

// ---------------------------------------------------------------------------
// Fallback attention kernels (used only if workspace too small for A_c/A_p)
// ---------------------------------------------------------------------------
__global__ __launch_bounds__(256) void attn1(
    const float* u_c, const u16* insenc, u16* qattn, u16* qbuf) {
  int b = blockIdx.x, tid = threadIdx.x;
  __shared__ float su[512], red[256], aw[64];
  for (int d = tid; d < 512; d += 256) su[d] = u_c[b * 512 + d];
  __syncthreads();
  {
    int l = tid >> 2, part = tid & 3;
    const u16* row = insenc + ((size_t)b * 64 + l) * 512 + part * 128;
    float s = 0.f;
    for (int k = 0; k < 128; k += 8) {
      bf16x8 v = load8(row + k);
#pragma unroll
      for (int e = 0; e < 8; e++) s += bf2f((u16)v[e]) * su[part * 128 + k + e];
    }
    red[tid] = s;
  }
  __syncthreads();
  if (tid < 64) {
    float sc = red[tid * 4] + red[tid * 4 + 1] + red[tid * 4 + 2] + red[tid * 4 + 3];
    float m = sc;
    for (int off = 32; off > 0; off >>= 1) m = fmaxf(m, __shfl_xor(m, off));
    float e = __expf(sc - m);
    float sm = e;
    for (int off = 32; off > 0; off >>= 1) sm += __shfl_xor(sm, off);
    aw[tid] = e / sm;
  }
  __syncthreads();
  for (int d = tid; d < 512; d += 256) {
    float z = 0.f;
    for (int l = 0; l < 64; l++) z += aw[l] * bf2f(insenc[((size_t)b * 64 + l) * 512 + d]);
    u16 zb = f2bf(z);
    qattn[(size_t)b * 1024 + d] = zb;
    qbuf[(size_t)b * 1024 + 512 + d] = zb;
  }
}

__global__ __launch_bounds__(256) void attn2(
    const float* u_p, const u16* hisenc, u16* qattn) {
  int b = blockIdx.x, tid = threadIdx.x;
  __shared__ float su[512], red[256], aw[128], mr[2];
  for (int d = tid; d < 512; d += 256) su[d] = u_p[b * 512 + d];
  __syncthreads();
  {
    int l = tid >> 1, part = tid & 1;
    const u16* row = hisenc + ((size_t)b * 128 + l) * 512 + part * 256;
    float s = 0.f;
    for (int k = 0; k < 256; k += 8) {
      bf16x8 v = load8(row + k);
#pragma unroll
      for (int e = 0; e < 8; e++) s += bf2f((u16)v[e]) * su[part * 256 + k + e];
    }
    red[tid] = s;
  }
  __syncthreads();
  float sc = (tid < 128) ? red[tid * 2] + red[tid * 2 + 1] : 0.f;
  __syncthreads();
  if (tid < 128) red[tid] = sc;
  __syncthreads();
  if (tid < 64) {
    float m = fmaxf(red[tid], red[tid + 64]);
    for (int off = 32; off > 0; off >>= 1) m = fmaxf(m, __shfl_xor(m, off));
    if (tid == 0) mr[0] = m;
  }
  __syncthreads();
  float ex = 0.f;
  if (tid < 128) { ex = __expf(sc - mr[0]); red[tid] = ex; }
  __syncthreads();
  if (tid < 64) {
    float s2 = red[tid] + red[tid + 64];
    for (int off = 32; off > 0; off >>= 1) s2 += __shfl_xor(s2, off);
    if (tid == 0) mr[1] = s2;
  }
  __syncthreads();
  if (tid < 128) aw[tid] = ex / mr[1];
  __syncthreads();
  for (int d = tid; d < 512; d += 256) {
    float z = 0.f;
    for (int l = 0; l < 128; l++) z += aw[l] * bf2f(hisenc[((size_t)b * 128 + l) * 512 + d]);
    qattn[(size_t)b * 1024 + 512 + d] = f2bf(z);
  }
}

// decoder init: h0 -> zin[0] h-half + qbuf h-half; c0 -> c_ws
__global__ void dec_init(const float* h0, const float* c0, u16* zin0, u16* qbuf, float* c_ws) {
  int idx = blockIdx.x * 256 + threadIdx.x; // 128*512
  int b = idx >> 9, d = idx & 511;
  u16 hv = f2bf(h0[idx]);
  zin0[(size_t)b * 1024 + 512 + d] = hv;
  qbuf[(size_t)b * 1024 + d] = hv;
  c_ws[idx] = c0[idx];
}

// ---------------------------------------------------------------------------
extern "C" void kernel_launch(void* const* d_in, const int* in_sizes, int n_in,
                              void* d_out, int out_size, void* d_ws, size_t ws_size,
                              hipStream_t stream) {
  const int* ins_tok = (const int*)d_in[0];
  const int* his_tok = (const int*)d_in[1];
  const int* actions = (const int*)d_in[2];
  const int* cur_env = (const int*)d_in[3];
  const int* ini_env = (const int*)d_in[4];
  const float* enc_emb = (const float*)d_in[5];
  const float* Wih_f = (const float*)d_in[6];
  const float* Whh_f = (const float*)d_in[7];
  const float* bih_f = (const float*)d_in[8];
  const float* bhh_f = (const float*)d_in[9];
  const float* Wih_b = (const float*)d_in[10];
  const float* Whh_b = (const float*)d_in[11];
  const float* bih_b = (const float*)d_in[12];
  const float* bhh_b = (const float*)d_in[13];
  const float* color_emb = (const float*)d_in[14];
  const float* pos_emb = (const float*)d_in[15];
  const float* ws_Wih = (const float*)d_in[16];
  const float* ws_Whh = (const float*)d_in[17];
  const float* ws_bih = (const float*)d_in[18];
  const float* ws_bhh = (const float*)d_in[19];
  const float* act_emb = (const float*)d_in[20];
  const float* W_c = (const float*)d_in[21];
  const float* W_p = (const float*)d_in[22];
  // d_in[23..26] (W_sb1/W_sb2/W_sc1/W_sc2) are mathematically dead (uniform softmax).
  const float* Wbd_W = (const float*)d_in[27];
  const float* Wbd_b = (const float*)d_in[28];
  const float* dec_Wih = (const float*)d_in[29];
  const float* dec_Whh = (const float*)d_in[30];
  const float* dec_bih = (const float*)d_in[31];
  const float* dec_bhh = (const float*)d_in[32];
  const float* h2a_W = (const float*)d_in[33];
  const float* h2a_b = (const float*)d_in[34];
  const float* h0 = (const float*)d_in[35];
  const float* c0 = (const float*)d_in[36];
  (void)in_sizes; (void)n_in; (void)out_size;

  char* ws = (char*)d_ws;
  size_t off = 0;
  auto alloc = [&](size_t bytes) -> char* {
    char* p = ws + off;
    off = (off + bytes + 255) & ~(size_t)255;
    return p;
  };
  u16* insenc   = (u16*)alloc(8192ull * 512 * 2);
  u16* hisenc   = (u16*)alloc(16384ull * 512 * 2);
  u16* outs     = (u16*)alloc(4096ull * 512 * 2);
  u16* Wsum     = (u16*)alloc(512ull * 896 * 2);
  float* projact= (float*)alloc(100ull * 512 * 4);
  float* bias_f = (float*)alloc(1024 * 4);
  float* bias_b = (float*)alloc(1024 * 4);
  float* bdecint= (float*)alloc(2048 * 4);
  float* bwbd   = (float*)alloc(512 * 4);
  float* bh2a   = (float*)alloc(128 * 4);
  u16* ctxcat   = (u16*)alloc(128ull * 896 * 2);
  float* hkbase = (float*)alloc(128ull * 512 * 4);
  float* u_c    = (float*)alloc(128ull * 512 * 4);   // fallback only
  float* u_p    = (float*)alloc(128ull * 512 * 4);   // fallback only
  u16* qbuf     = (u16*)alloc(128ull * 1024 * 2);     // [h | z_c]
  u16* qattn    = (u16*)alloc(128ull * 1024 * 2);     // [z_c | z_p]
  u16* zin      = (u16*)alloc(2ull * 128 * 1024 * 2); // [hk | h], parity
  float* c_dec  = (float*)alloc(128ull * 512 * 4);
  // bf16 weight copies
  u16* emb_bf   = (u16*)alloc(2000ull * 128 * 2);
  u16* wihf_bf  = (u16*)alloc(1024ull * 128 * 2);
  u16* wihb_bf  = (u16*)alloc(1024ull * 128 * 2);
  u16* whhf_bf  = (u16*)alloc(1024ull * 256 * 2);
  u16* whhb_bf  = (u16*)alloc(1024ull * 256 * 2);
  u16* act_bf   = (u16*)alloc(100ull * 128 * 2);
  u16* wc_bf    = (u16*)alloc(512ull * 512 * 2);      // fallback only
  u16* wp_bf    = (u16*)alloc(512ull * 1024 * 2);     // fallback only
  u16* wcT_bf   = (u16*)alloc(512ull * 512 * 2);      // W_c^T (fused path)
  u16* wpT_bf   = (u16*)alloc(1024ull * 512 * 2);     // W_p^T (fused path)
  u16* wbd01_bf = (u16*)alloc(512ull * 1024 * 2);
  u16* wbdx_bf  = (u16*)alloc(512ull * 128 * 2);
  u16* dwih_bf  = (u16*)alloc(2048ull * 512 * 2);
  u16* dwhh_bf  = (u16*)alloc(2048ull * 512 * 2);
  u16* h2a_bf   = (u16*)alloc(100ull * 512 * 2);
  // t-invariant attention projections (large): last, guarded by ws_size.
  u16* A_c = (u16*)alloc(8192ull * 512 * 2);    // 8.4 MB
  u16* A_p = (u16*)alloc(16384ull * 1024 * 2);  // 33.6 MB
  bool fused = (off <= ws_size);

  // --- weight conversions (f32 -> bf16) ---
  auto cvt = [&](const float* src, u16* dst, int R, int C, int ld, int c0c) {
    int n = R * C;
    cvt_slice<<<(n + 255) / 256, 256, 0, stream>>>(src, ld, c0c, dst, R, C);
  };
  cvt(enc_emb, emb_bf, 2000, 128, 128, 0);
  cvt(Wih_f, wihf_bf, 1024, 128, 128, 0);
  cvt(Wih_b, wihb_bf, 1024, 128, 128, 0);
  cvt(Whh_f, whhf_bf, 1024, 256, 256, 0);
  cvt(Whh_b, whhb_bf, 1024, 256, 256, 0);
  cvt(act_emb, act_bf, 100, 128, 128, 0);
  if (fused) {
    cvtT<<<(512 * 512 + 255) / 256, 256, 0, stream>>>(W_c, wcT_bf, 512, 512);
    cvtT<<<(512 * 1024 + 255) / 256, 256, 0, stream>>>(W_p, wpT_bf, 512, 1024);
  } else {
    cvt(W_c, wc_bf, 512, 512, 512, 0);
    cvt(W_p, wp_bf, 512, 1024, 1024, 0);
  }
  cvt(Wbd_W, wbd01_bf, 512, 1024, 2944, 0);
  cvt(Wbd_W, wbdx_bf, 512, 128, 2944, 2816);
  cvt(dec_Wih, dwih_bf, 2048, 512, 512, 0);
  cvt(dec_Whh, dwhh_bf, 2048, 512, 512, 0);
  cvt(h2a_W, h2a_bf, 100, 512, 512, 0);

  // --- bias prep ---
  addcvt<<<4, 256, 0, stream>>>(bih_f, bhh_f, bias_f, 1024);
  addcvt<<<4, 256, 0, stream>>>(bih_b, bhh_b, bias_b, 1024);
  addcvt<<<2, 256, 0, stream>>>(Wbd_b, nullptr, bwbd, 512);
  addcvt<<<1, 256, 0, stream>>>(h2a_b, nullptr, bh2a, 100);
  bdecint_build<<<8, 256, 0, stream>>>(dec_bih, dec_bhh, bdecint);
  wsum_build<<<1792, 256, 0, stream>>>(Wbd_W, Wsum);

  // --- proj_act = act_emb @ Wbd_x^T + Wbd_b ---
  GemmArgs gp = {};
  gp.A = act_bf; gp.lda = 128; gp.M = 100; gp.W = wbdx_bf; gp.ldw = 128;
  gp.N = 512; gp.K = 128; gp.out = projact; gp.ldc = 512; gp.bias = bwbd;
  gemm_k<0><<<dim3(2, 8), 256, 0, stream>>>(gp);

  // --- env encode + hk_base ---
  env_encode<<<224, 256, 0, stream>>>(cur_env, ini_env, color_emb, pos_emb,
                                      ws_Wih, ws_Whh, ws_bih, ws_bhh, ctxcat);
  GemmArgs gb = {};
  gb.A = ctxcat; gb.lda = 896; gb.M = 128; gb.W = Wsum; gb.ldw = 896;
  gb.N = 512; gb.K = 896; gb.out = hkbase; gb.ldc = 512;
  gemm_k<0><<<dim3(2, 8), 256, 0, stream>>>(gb);

  // --- encoder: ONE persistent launch (was 128 sequential launches) ---
  enc_persist<<<32, 256, 0, stream>>>(ins_tok, his_tok, emb_bf,
                                      wihf_bf, wihb_bf, whhf_bf, whhb_bf,
                                      bias_f, bias_b, insenc, hisenc);

  // --- t-invariant attention projections (fused path) ---
  if (fused) {
    GemmArgs ga = {};
    ga.A = insenc; ga.lda = 512; ga.M = 8192; ga.W = wcT_bf; ga.ldw = 512;
    ga.N = 512; ga.K = 512; ga.out = A_c; ga.ldc = 512;
    gemm_k<1><<<dim3(128, 8), 256, 0, stream>>>(ga);
    GemmArgs ga2 = {};
    ga2.A = hisenc; ga2.lda = 512; ga2.M = 16384; ga2.W = wpT_bf; ga2.ldw = 512;
    ga2.N = 1024; ga2.K = 512; ga2.out = A_p; ga2.ldc = 1024;
    gemm_k<1><<<dim3(256, 16), 256, 0, stream>>>(ga2);
  }

  // --- decoder ---
  dec_init<<<256, 256, 0, stream>>>(h0, c0, zin, qbuf, c_dec);
  for (int t = 0; t < 32; t++) {
    u16* zin_cur = zin + (size_t)(t & 1) * 128 * 1024;
    u16* zin_nxt = zin + (size_t)((t + 1) & 1) * 128 * 1024;
    if (fused) {
      // one kernel replaces u_c GEMM + attn1 + u_p GEMM + attn2
      attn_both<<<128, 256, 0, stream>>>(qbuf, A_c, insenc, A_p, hisenc, qattn);
    } else {
      GemmArgs gu = {};
      gu.A = qbuf; gu.lda = 1024; gu.M = 128; gu.W = wc_bf; gu.ldw = 512;
      gu.N = 512; gu.K = 512; gu.out = u_c; gu.ldc = 512;
      gemm_k<0><<<dim3(2, 8), 256, 0, stream>>>(gu);
      attn1<<<128, 256, 0, stream>>>(u_c, insenc, qattn, qbuf);
      GemmArgs gv = {};
      gv.A = qbuf; gv.lda = 1024; gv.M = 128; gv.W = wp_bf; gv.ldw = 1024;
      gv.N = 512; gv.K = 1024; gv.out = u_p; gv.ldc = 512;
      gemm_k<0><<<dim3(2, 8), 256, 0, stream>>>(gv);
      attn2<<<128, 256, 0, stream>>>(u_p, hisenc, qattn);
    }
    // hk = tanh([z_c|z_p]@Wbd[:,0:1024]^T + hk_base + proj_act[action])
    GemmArgs gh = {};
    gh.A = qattn; gh.lda = 1024; gh.M = 128; gh.W = wbd01_bf; gh.ldw = 1024;
    gh.N = 512; gh.K = 1024; gh.out = zin_cur; gh.ldc = 1024;
    gh.hk_base = hkbase; gh.proj_act = projact; gh.actions = actions; gh.t = t;
    gemm_k<2><<<dim3(2, 8), 256, 0, stream>>>(gh);
    // gates + fused cell
    dec_gates_cell<<<dim3(2, 32), 256, 0, stream>>>(
        zin_cur, dwih_bf, dwhh_bf, bdecint, c_dec, zin_nxt, qbuf, outs, t);
  }

  // --- logits (f32 out) ---
  GemmArgs gl = {};
  gl.A = outs; gl.lda = 512; gl.M = 4096; gl.W = h2a_bf; gl.ldw = 512;
  gl.N = 100; gl.K = 512; gl.out = d_out; gl.ldc = 100; gl.bias = bh2a;
  gemm_k<0><<<dim3(64, 2), 256, 0, stream>>>(gl);
}